// Round 1
// baseline (77.654 us; speedup 1.0000x reference)
//
#include <hip/hip_runtime.h>
#include <math.h>

// Problem constants (from setup_inputs: B=16, N=131072, C=2)
#define BATCH 16
#define NPB 131072
#define BLOCKS_PER_B 128
#define THREADS 256
#define PPT (NPB / (BLOCKS_PER_B * THREADS))   // 4 points per thread
#define NACC 54   // 21 (Hpp sym) + 6 (g_p) + 21 (S_hh sym) + 6 (S_hg)

__device__ __forceinline__ float safe_lambda(float l) {
    if (isnan(l)) l = 100.0f;
    return fmaxf(l, 0.001f);
}

// ---------------- Pass 1: per-batch reductions ----------------
__global__ __launch_bounds__(THREADS) void dba_pass1(
    const float* __restrict__ r, const float* __restrict__ w,
    const float* __restrict__ Jp, const float* __restrict__ Jd,
    const float* __restrict__ lmbda, float* __restrict__ partials)
{
    const int b   = blockIdx.y;
    const int blk = blockIdx.x;
    const int t   = threadIdx.x;
    const float lam = safe_lambda(lmbda[b]);

    float acc[NACC];
#pragma unroll
    for (int i = 0; i < NACC; ++i) acc[i] = 0.0f;

    const long base = (long)b * NPB + (long)blk * (THREADS * PPT);

    for (int it = 0; it < PPT; ++it) {
        const long n = base + (long)it * THREADS + t;
        const float4* jp4 = (const float4*)(Jp + n * 12);
        float4 a0 = jp4[0], a1 = jp4[1], a2 = jp4[2];
        float jp[12] = {a0.x,a0.y,a0.z,a0.w, a1.x,a1.y,a1.z,a1.w, a2.x,a2.y,a2.z,a2.w};
        float2 jd = *(const float2*)(Jd + n * 2);
        float2 rv = *(const float2*)(r  + n * 2);
        float2 wv = *(const float2*)(w  + n * 2);
        const float conf = wv.x;
        const float nl   = wv.y;

        float h[6];
#pragma unroll
        for (int p = 0; p < 6; ++p) h[p] = conf * (jp[p]*jd.x + jp[6+p]*jd.y);
        const float Hdd = conf * (jd.x*jd.x + jd.y*jd.y);
        const float gd  = conf * (jd.x*rv.x + jd.y*rv.y);
        const float inv = 1.0f / fmaxf(Hdd + lam + nl + 1e-4f, 1e-4f);

        int idx = 0;
#pragma unroll
        for (int p = 0; p < 6; ++p)
#pragma unroll
            for (int q = p; q < 6; ++q)
                acc[idx++] += conf * (jp[p]*jp[q] + jp[6+p]*jp[6+q]);
#pragma unroll
        for (int p = 0; p < 6; ++p)
            acc[21 + p] += conf * (jp[p]*rv.x + jp[6+p]*rv.y);
        idx = 27;
#pragma unroll
        for (int p = 0; p < 6; ++p) {
            const float hi = h[p] * inv;
#pragma unroll
            for (int q = p; q < 6; ++q)
                acc[idx++] += hi * h[q];
        }
        const float ginv = gd * inv;
#pragma unroll
        for (int p = 0; p < 6; ++p)
            acc[48 + p] += h[p] * ginv;
    }

    // wave-64 butterfly reduce
#pragma unroll
    for (int i = 0; i < NACC; ++i) {
        float v = acc[i];
        v += __shfl_xor(v, 1);
        v += __shfl_xor(v, 2);
        v += __shfl_xor(v, 4);
        v += __shfl_xor(v, 8);
        v += __shfl_xor(v, 16);
        v += __shfl_xor(v, 32);
        acc[i] = v;
    }

    // cross-wave reduce via LDS (4 waves)
    __shared__ float s_red[4][NACC];
    const int wid  = t >> 6;
    const int lane = t & 63;
    if (lane == 0) {
        for (int i = 0; i < NACC; ++i) s_red[wid][i] = acc[i];
    }
    __syncthreads();
    if (t < NACC) {
        float v = s_red[0][t] + s_red[1][t] + s_red[2][t] + s_red[3][t];
        partials[((long)b * BLOCKS_PER_B + blk) * NACC + t] = v;
    }
}

// ---------------- Pass 2: assemble + 6x6 solve per batch ----------------
__global__ void dba_solve(
    const float* __restrict__ partials, const float* __restrict__ lmbda,
    const int* __restrict__ iter_idx,
    float* __restrict__ out_pose,      // d_out[0:96], clipped
    float* __restrict__ dp_raw)        // ws, unclipped (for pass 3)
{
    const int b = blockIdx.x;
    const int t = threadIdx.x;   // 64 threads
    __shared__ float s[NACC];
    if (t < NACC) {
        float v = 0.0f;
        for (int k = 0; k < BLOCKS_PER_B; ++k)
            v += partials[((long)b * BLOCKS_PER_B + k) * NACC + t];
        s[t] = v;
    }
    __syncthreads();
    if (t != 0) return;

    const float lam = safe_lambda(lmbda[b]);
    float H[6][6], g[6];
    int idx = 0;
    for (int p = 0; p < 6; ++p)
        for (int q = p; q < 6; ++q) {
            float v = s[idx] - s[27 + idx];   // Hpp - term_to_sub (same sym order)
            H[p][q] = v; H[q][p] = v;
            idx++;
        }
    for (int p = 0; p < 6; ++p) g[p] = s[21 + p] - s[48 + p];
    for (int p = 0; p < 6; ++p) H[p][p] += lam;

    if (*iter_idx >= 2) {
        for (int p = 3; p < 6; ++p) g[p] = 0.0f;
        for (int p = 3; p < 6; ++p)
            for (int q = 3; q < 6; ++q) H[p][q] += 1e8f;
    }
    for (int p = 0; p < 6; ++p) H[p][p] += 1.0f;
    for (int p = 0; p < 6; ++p) H[p][p] += 0.01f * H[p][p];

    // Gaussian elimination with partial pivoting, augmented column = g
    float A[6][7];
    for (int p = 0; p < 6; ++p) {
        for (int q = 0; q < 6; ++q) A[p][q] = H[p][q];
        A[p][6] = g[p];
    }
    for (int col = 0; col < 6; ++col) {
        int piv = col; float best = fabsf(A[col][col]);
        for (int rr = col + 1; rr < 6; ++rr) {
            float v = fabsf(A[rr][col]);
            if (v > best) { best = v; piv = rr; }
        }
        if (piv != col)
            for (int cc = col; cc < 7; ++cc) {
                float tmp = A[col][cc]; A[col][cc] = A[piv][cc]; A[piv][cc] = tmp;
            }
        const float invp = 1.0f / A[col][col];
        for (int rr = col + 1; rr < 6; ++rr) {
            const float f = A[rr][col] * invp;
            for (int cc = col; cc < 7; ++cc) A[rr][cc] -= f * A[col][cc];
        }
    }
    float x[6];
    for (int rr = 5; rr >= 0; --rr) {
        float v = A[rr][6];
        for (int cc = rr + 1; cc < 6; ++cc) v -= A[rr][cc] * x[cc];
        x[rr] = v / A[rr][rr];
    }
    for (int p = 0; p < 6; ++p) {
        dp_raw[b * 6 + p] = x[p];                       // unclipped, feeds pass 3
        out_pose[b * 6 + p] = fminf(fmaxf(x[p], -2.0f), 2.0f);
    }
}

// ---------------- Pass 3: delta_depth per point ----------------
__global__ __launch_bounds__(THREADS) void dba_pass3(
    const float* __restrict__ r, const float* __restrict__ w,
    const float* __restrict__ Jp, const float* __restrict__ Jd,
    const float* __restrict__ lmbda, const float* __restrict__ dp_raw,
    float* __restrict__ out_dd)
{
    const int b   = blockIdx.y;
    const int blk = blockIdx.x;
    const int t   = threadIdx.x;
    const float lam = safe_lambda(lmbda[b]);

    float dp[6];
#pragma unroll
    for (int p = 0; p < 6; ++p) dp[p] = dp_raw[b * 6 + p];

    const long base = (long)b * NPB + (long)blk * (THREADS * PPT);
    for (int it = 0; it < PPT; ++it) {
        const long n = base + (long)it * THREADS + t;
        const float4* jp4 = (const float4*)(Jp + n * 12);
        float4 a0 = jp4[0], a1 = jp4[1], a2 = jp4[2];
        float jp[12] = {a0.x,a0.y,a0.z,a0.w, a1.x,a1.y,a1.z,a1.w, a2.x,a2.y,a2.z,a2.w};
        float2 jd = *(const float2*)(Jd + n * 2);
        float2 rv = *(const float2*)(r  + n * 2);
        float2 wv = *(const float2*)(w  + n * 2);
        const float conf = wv.x;
        const float nl   = wv.y;

        float v = 0.0f;
#pragma unroll
        for (int p = 0; p < 6; ++p) {
            const float h = conf * (jp[p]*jd.x + jp[6+p]*jd.y);
            v += h * dp[p];
        }
        const float Hdd = conf * (jd.x*jd.x + jd.y*jd.y);
        const float gd  = conf * (jd.x*rv.x + jd.y*rv.y);
        const float inv = 1.0f / fmaxf(Hdd + lam + nl + 1e-4f, 1e-4f);
        float dd = inv * (gd - v);
        dd = fminf(fmaxf(dd, -5.0f), 5.0f);
        out_dd[n] = dd;
    }
}

extern "C" void kernel_launch(void* const* d_in, const int* in_sizes, int n_in,
                              void* d_out, int out_size, void* d_ws, size_t ws_size,
                              hipStream_t stream) {
    const float* r     = (const float*)d_in[0];
    const float* w     = (const float*)d_in[1];
    const float* Jp    = (const float*)d_in[2];
    const float* Jd    = (const float*)d_in[3];
    const float* lmbda = (const float*)d_in[4];
    const int*   iter  = (const int*)  d_in[5];

    float* out      = (float*)d_out;           // [0:96) delta_pose, [96:) delta_depth
    float* partials = (float*)d_ws;            // BATCH * BLOCKS_PER_B * NACC floats
    float* dp_raw   = partials + (long)BATCH * BLOCKS_PER_B * NACC;  // BATCH*6 floats

    dim3 grid(BLOCKS_PER_B, BATCH);
    dba_pass1<<<grid, THREADS, 0, stream>>>(r, w, Jp, Jd, lmbda, partials);
    dba_solve<<<BATCH, 64, 0, stream>>>(partials, lmbda, iter, out, dp_raw);
    dba_pass3<<<grid, THREADS, 0, stream>>>(r, w, Jp, Jd, lmbda, dp_raw, out + BATCH * 6);
}

// Round 2
// 77.321 us; speedup vs baseline: 1.0043x; 1.0043x over previous
//
#include <hip/hip_runtime.h>
#include <math.h>

// Problem constants (from setup_inputs: B=16, N=131072, C=2)
#define BATCH 16
#define NPB 131072
#define BLOCKS_PER_B 128
#define THREADS 256
#define PPT (NPB / (BLOCKS_PER_B * THREADS))   // 4 points per thread
#define NACC 27   // 21 (Heff_partial sym) + 6 (g_eff_partial)

__device__ __forceinline__ float safe_lambda(float l) {
    if (isnan(l)) l = 100.0f;
    return fmaxf(l, 0.001f);
}

struct Pt { float4 a0, a1, a2; float2 jd, rv, wv; };

__device__ __forceinline__ void load_pt(const float* __restrict__ Jp, const float* __restrict__ Jd,
                                        const float* __restrict__ r, const float* __restrict__ w,
                                        long n, Pt& P)
{
    const float4* jp4 = (const float4*)(Jp + n * 12);
    P.a0 = jp4[0]; P.a1 = jp4[1]; P.a2 = jp4[2];
    P.jd = *(const float2*)(Jd + n * 2);
    P.rv = *(const float2*)(r  + n * 2);
    P.wv = *(const float2*)(w  + n * 2);
}

// Accumulate Heff_partial = conf*Jp.Jp^T - h*inv*h^T  and  geff_partial = conf*Jp.r - h*inv*gd
__device__ __forceinline__ void acc_pt(const Pt& P, float lam, float (&D)[21], float (&G)[6])
{
    float jp[12] = {P.a0.x, P.a0.y, P.a0.z, P.a0.w,
                    P.a1.x, P.a1.y, P.a1.z, P.a1.w,
                    P.a2.x, P.a2.y, P.a2.z, P.a2.w};
    const float conf = P.wv.x, nl = P.wv.y;
    const float jdx = P.jd.x, jdy = P.jd.y;
    const float rx  = P.rv.x, ry  = P.rv.y;

    float h[6], hi[6];
#pragma unroll
    for (int p = 0; p < 6; ++p) h[p] = conf * (jp[p] * jdx + jp[6 + p] * jdy);
    const float Hdd = conf * (jdx * jdx + jdy * jdy);
    const float gd  = conf * (jdx * rx + jdy * ry);
    const float inv = 1.0f / fmaxf(Hdd + lam + nl + 1e-4f, 1e-4f);
#pragma unroll
    for (int p = 0; p < 6; ++p) hi[p] = h[p] * inv;

    int idx = 0;
#pragma unroll
    for (int p = 0; p < 6; ++p) {
#pragma unroll
        for (int q = p; q < 6; ++q) {
            D[idx] += conf * (jp[p] * jp[q] + jp[6 + p] * jp[6 + q]) - hi[p] * h[q];
            ++idx;
        }
    }
#pragma unroll
    for (int p = 0; p < 6; ++p)
        G[p] += conf * (jp[p] * rx + jp[6 + p] * ry) - hi[p] * gd;
}

// ---------------- Pass 1: per-batch reductions ----------------
__global__ __launch_bounds__(THREADS, 4) void dba_pass1(
    const float* __restrict__ r, const float* __restrict__ w,
    const float* __restrict__ Jp, const float* __restrict__ Jd,
    const float* __restrict__ lmbda, float* __restrict__ partials)
{
    const int b   = blockIdx.y;
    const int blk = blockIdx.x;
    const int t   = threadIdx.x;
    const float lam = safe_lambda(lmbda[b]);

    float D[21], G[6];
#pragma unroll
    for (int i = 0; i < 21; ++i) D[i] = 0.0f;
#pragma unroll
    for (int i = 0; i < 6; ++i) G[i] = 0.0f;

    const long base = (long)b * NPB + (long)blk * (THREADS * PPT) + t;

    // 2-deep software pipeline over PPT=4 points
    Pt A, B;
    load_pt(Jp, Jd, r, w, base + 0 * THREADS, A);
    load_pt(Jp, Jd, r, w, base + 1 * THREADS, B);
    acc_pt(A, lam, D, G);
    load_pt(Jp, Jd, r, w, base + 2 * THREADS, A);
    acc_pt(B, lam, D, G);
    load_pt(Jp, Jd, r, w, base + 3 * THREADS, B);
    acc_pt(A, lam, D, G);
    acc_pt(B, lam, D, G);

    // wave-64 butterfly reduce (27 values)
#pragma unroll
    for (int i = 0; i < 21; ++i) {
        float v = D[i];
        v += __shfl_xor(v, 1);  v += __shfl_xor(v, 2);  v += __shfl_xor(v, 4);
        v += __shfl_xor(v, 8);  v += __shfl_xor(v, 16); v += __shfl_xor(v, 32);
        D[i] = v;
    }
#pragma unroll
    for (int i = 0; i < 6; ++i) {
        float v = G[i];
        v += __shfl_xor(v, 1);  v += __shfl_xor(v, 2);  v += __shfl_xor(v, 4);
        v += __shfl_xor(v, 8);  v += __shfl_xor(v, 16); v += __shfl_xor(v, 32);
        G[i] = v;
    }

    // cross-wave reduce via LDS (4 waves)
    __shared__ float s_red[4][NACC];
    const int wid  = t >> 6;
    const int lane = t & 63;
    if (lane == 0) {
#pragma unroll
        for (int i = 0; i < 21; ++i) s_red[wid][i] = D[i];
#pragma unroll
        for (int i = 0; i < 6; ++i)  s_red[wid][21 + i] = G[i];
    }
    __syncthreads();
    if (t < NACC) {
        float v = s_red[0][t] + s_red[1][t] + s_red[2][t] + s_red[3][t];
        // transposed layout: [b][counter][block] -> contiguous rows for the solve
        partials[((long)b * NACC + t) * BLOCKS_PER_B + blk] = v;
    }
}

// ---------------- Pass 2: assemble + 6x6 solve per batch ----------------
__global__ void dba_solve(
    const float* __restrict__ partials, const float* __restrict__ lmbda,
    const int* __restrict__ iter_idx,
    float* __restrict__ out_pose,      // d_out[0:96], clipped
    float* __restrict__ dp_raw)        // ws, unclipped (for pass 3)
{
    const int b = blockIdx.x;
    const int t = threadIdx.x;   // 64 threads
    __shared__ float s[NACC];
    if (t < NACC) {
        const float4* p4 = (const float4*)(partials + ((long)b * NACC + t) * BLOCKS_PER_B);
        float4 a = make_float4(0.f, 0.f, 0.f, 0.f);
#pragma unroll
        for (int k = 0; k < BLOCKS_PER_B / 4; ++k) {
            float4 v = p4[k];
            a.x += v.x; a.y += v.y; a.z += v.z; a.w += v.w;
        }
        s[t] = (a.x + a.y) + (a.z + a.w);
    }
    __syncthreads();
    if (t != 0) return;

    const float lam = safe_lambda(lmbda[b]);
    float H[6][6], g[6];
    int idx = 0;
    for (int p = 0; p < 6; ++p)
        for (int q = p; q < 6; ++q) {
            float v = s[idx];                 // already Hpp - term_to_sub
            H[p][q] = v; H[q][p] = v;
            idx++;
        }
    for (int p = 0; p < 6; ++p) g[p] = s[21 + p];
    for (int p = 0; p < 6; ++p) H[p][p] += lam;

    if (*iter_idx >= 2) {
        for (int p = 3; p < 6; ++p) g[p] = 0.0f;
        for (int p = 3; p < 6; ++p)
            for (int q = 3; q < 6; ++q) H[p][q] += 1e8f;
    }
    for (int p = 0; p < 6; ++p) H[p][p] += 1.0f;
    for (int p = 0; p < 6; ++p) H[p][p] += 0.01f * H[p][p];

    // Gaussian elimination with partial pivoting, augmented column = g
    float A[6][7];
    for (int p = 0; p < 6; ++p) {
        for (int q = 0; q < 6; ++q) A[p][q] = H[p][q];
        A[p][6] = g[p];
    }
    for (int col = 0; col < 6; ++col) {
        int piv = col; float best = fabsf(A[col][col]);
        for (int rr = col + 1; rr < 6; ++rr) {
            float v = fabsf(A[rr][col]);
            if (v > best) { best = v; piv = rr; }
        }
        if (piv != col)
            for (int cc = col; cc < 7; ++cc) {
                float tmp = A[col][cc]; A[col][cc] = A[piv][cc]; A[piv][cc] = tmp;
            }
        const float invp = 1.0f / A[col][col];
        for (int rr = col + 1; rr < 6; ++rr) {
            const float f = A[rr][col] * invp;
            for (int cc = col; cc < 7; ++cc) A[rr][cc] -= f * A[col][cc];
        }
    }
    float x[6];
    for (int rr = 5; rr >= 0; --rr) {
        float v = A[rr][6];
        for (int cc = rr + 1; cc < 6; ++cc) v -= A[rr][cc] * x[cc];
        x[rr] = v / A[rr][rr];
    }
    for (int p = 0; p < 6; ++p) {
        dp_raw[b * 6 + p] = x[p];                       // unclipped, feeds pass 3
        out_pose[b * 6 + p] = fminf(fmaxf(x[p], -2.0f), 2.0f);
    }
}

// ---------------- Pass 3: delta_depth per point ----------------
__device__ __forceinline__ float depth_pt(const Pt& P, float lam, const float (&dp)[6])
{
    float jp[12] = {P.a0.x, P.a0.y, P.a0.z, P.a0.w,
                    P.a1.x, P.a1.y, P.a1.z, P.a1.w,
                    P.a2.x, P.a2.y, P.a2.z, P.a2.w};
    const float conf = P.wv.x, nl = P.wv.y;
    const float jdx = P.jd.x, jdy = P.jd.y;
    const float rx  = P.rv.x, ry  = P.rv.y;

    float v = 0.0f;
#pragma unroll
    for (int p = 0; p < 6; ++p) {
        const float h = conf * (jp[p] * jdx + jp[6 + p] * jdy);
        v += h * dp[p];
    }
    const float Hdd = conf * (jdx * jdx + jdy * jdy);
    const float gd  = conf * (jdx * rx + jdy * ry);
    const float inv = 1.0f / fmaxf(Hdd + lam + nl + 1e-4f, 1e-4f);
    float dd = inv * (gd - v);
    return fminf(fmaxf(dd, -5.0f), 5.0f);
}

__global__ __launch_bounds__(THREADS, 4) void dba_pass3(
    const float* __restrict__ r, const float* __restrict__ w,
    const float* __restrict__ Jp, const float* __restrict__ Jd,
    const float* __restrict__ lmbda, const float* __restrict__ dp_raw,
    float* __restrict__ out_dd)
{
    const int b   = blockIdx.y;
    const int blk = blockIdx.x;
    const int t   = threadIdx.x;
    const float lam = safe_lambda(lmbda[b]);

    float dp[6];
#pragma unroll
    for (int p = 0; p < 6; ++p) dp[p] = dp_raw[b * 6 + p];

    const long base = (long)b * NPB + (long)blk * (THREADS * PPT) + t;

    Pt A, B;
    load_pt(Jp, Jd, r, w, base + 0 * THREADS, A);
    load_pt(Jp, Jd, r, w, base + 1 * THREADS, B);
    out_dd[base + 0 * THREADS] = depth_pt(A, lam, dp);
    load_pt(Jp, Jd, r, w, base + 2 * THREADS, A);
    out_dd[base + 1 * THREADS] = depth_pt(B, lam, dp);
    load_pt(Jp, Jd, r, w, base + 3 * THREADS, B);
    out_dd[base + 2 * THREADS] = depth_pt(A, lam, dp);
    out_dd[base + 3 * THREADS] = depth_pt(B, lam, dp);
}

extern "C" void kernel_launch(void* const* d_in, const int* in_sizes, int n_in,
                              void* d_out, int out_size, void* d_ws, size_t ws_size,
                              hipStream_t stream) {
    const float* r     = (const float*)d_in[0];
    const float* w     = (const float*)d_in[1];
    const float* Jp    = (const float*)d_in[2];
    const float* Jd    = (const float*)d_in[3];
    const float* lmbda = (const float*)d_in[4];
    const int*   iter  = (const int*)  d_in[5];

    float* out      = (float*)d_out;           // [0:96) delta_pose, [96:) delta_depth
    float* partials = (float*)d_ws;            // BATCH * NACC * BLOCKS_PER_B floats
    float* dp_raw   = partials + (long)BATCH * NACC * BLOCKS_PER_B;  // BATCH*6 floats

    dim3 grid(BLOCKS_PER_B, BATCH);
    dba_pass1<<<grid, THREADS, 0, stream>>>(r, w, Jp, Jd, lmbda, partials);
    dba_solve<<<BATCH, 64, 0, stream>>>(partials, lmbda, iter, out, dp_raw);
    dba_pass3<<<grid, THREADS, 0, stream>>>(r, w, Jp, Jd, lmbda, dp_raw, out + BATCH * 6);
}

// Round 3
// 59.361 us; speedup vs baseline: 1.3082x; 1.3026x over previous
//
#include <hip/hip_runtime.h>
#include <math.h>

// Problem constants (from setup_inputs: B=16, N=131072, C=2)
#define BATCH 16
#define NPB 131072
#define BLOCKS_PER_B 64
#define THREADS 256
#define PPT (NPB / (BLOCKS_PER_B * THREADS))   // 8 points per thread
#define NACC 27   // 21 (Heff_partial sym) + 6 (g_eff_partial)

__device__ __forceinline__ float safe_lambda(float l) {
    if (isnan(l)) l = 100.0f;
    return fmaxf(l, 0.001f);
}

struct Pt { float4 a0, a1, a2; float2 jd, rv, wv; };

__device__ __forceinline__ void load_pt(const float* __restrict__ Jp, const float* __restrict__ Jd,
                                        const float* __restrict__ r, const float* __restrict__ w,
                                        long n, Pt& P)
{
    const float4* jp4 = (const float4*)(Jp + n * 12);
    P.a0 = jp4[0]; P.a1 = jp4[1]; P.a2 = jp4[2];
    P.jd = *(const float2*)(Jd + n * 2);
    P.rv = *(const float2*)(r  + n * 2);
    P.wv = *(const float2*)(w  + n * 2);
}

// Accumulate Heff_partial = conf*Jp.Jp^T - h*inv*h^T  and  geff_partial = conf*Jp.r - h*inv*gd
__device__ __forceinline__ void acc_pt(const Pt& P, float lam, float (&D)[21], float (&G)[6])
{
    float jp[12] = {P.a0.x, P.a0.y, P.a0.z, P.a0.w,
                    P.a1.x, P.a1.y, P.a1.z, P.a1.w,
                    P.a2.x, P.a2.y, P.a2.z, P.a2.w};
    const float conf = P.wv.x, nl = P.wv.y;
    const float jdx = P.jd.x, jdy = P.jd.y;
    const float rx  = P.rv.x, ry  = P.rv.y;

    float h[6], hi[6];
#pragma unroll
    for (int p = 0; p < 6; ++p) h[p] = conf * (jp[p] * jdx + jp[6 + p] * jdy);
    const float Hdd = conf * (jdx * jdx + jdy * jdy);
    const float gd  = conf * (jdx * rx + jdy * ry);
    const float inv = 1.0f / fmaxf(Hdd + lam + nl + 1e-4f, 1e-4f);
#pragma unroll
    for (int p = 0; p < 6; ++p) hi[p] = h[p] * inv;

    int idx = 0;
#pragma unroll
    for (int p = 0; p < 6; ++p) {
#pragma unroll
        for (int q = p; q < 6; ++q) {
            D[idx] += conf * (jp[p] * jp[q] + jp[6 + p] * jp[6 + q]) - hi[p] * h[q];
            ++idx;
        }
    }
#pragma unroll
    for (int p = 0; p < 6; ++p)
        G[p] += conf * (jp[p] * rx + jp[6 + p] * ry) - hi[p] * gd;
}

// ---------------- Pass 1: per-batch reductions ----------------
__global__ __launch_bounds__(THREADS, 2) void dba_pass1(
    const float* __restrict__ r, const float* __restrict__ w,
    const float* __restrict__ Jp, const float* __restrict__ Jd,
    const float* __restrict__ lmbda, float* __restrict__ partials)
{
    const int b   = blockIdx.y;
    const int blk = blockIdx.x;
    const int t   = threadIdx.x;
    const float lam = safe_lambda(lmbda[b]);

    float D[21], G[6];
#pragma unroll
    for (int i = 0; i < 21; ++i) D[i] = 0.0f;
#pragma unroll
    for (int i = 0; i < 6; ++i) G[i] = 0.0f;

    const long base = (long)b * NPB + (long)blk * (THREADS * PPT) + t;

    // 2-deep ping-pong software pipeline over PPT=8 points
    Pt A, B;
    load_pt(Jp, Jd, r, w, base + 0 * THREADS, A);
#pragma unroll
    for (int it = 0; it < PPT; it += 2) {
        load_pt(Jp, Jd, r, w, base + (it + 1) * THREADS, B);
        acc_pt(A, lam, D, G);
        if (it + 2 < PPT)
            load_pt(Jp, Jd, r, w, base + (it + 2) * THREADS, A);
        acc_pt(B, lam, D, G);
    }

    // wave-64 butterfly reduce (27 values)
#pragma unroll
    for (int i = 0; i < 21; ++i) {
        float v = D[i];
        v += __shfl_xor(v, 1);  v += __shfl_xor(v, 2);  v += __shfl_xor(v, 4);
        v += __shfl_xor(v, 8);  v += __shfl_xor(v, 16); v += __shfl_xor(v, 32);
        D[i] = v;
    }
#pragma unroll
    for (int i = 0; i < 6; ++i) {
        float v = G[i];
        v += __shfl_xor(v, 1);  v += __shfl_xor(v, 2);  v += __shfl_xor(v, 4);
        v += __shfl_xor(v, 8);  v += __shfl_xor(v, 16); v += __shfl_xor(v, 32);
        G[i] = v;
    }

    // cross-wave reduce via LDS (4 waves)
    __shared__ float s_red[4][NACC];
    const int wid  = t >> 6;
    const int lane = t & 63;
    if (lane == 0) {
#pragma unroll
        for (int i = 0; i < 21; ++i) s_red[wid][i] = D[i];
#pragma unroll
        for (int i = 0; i < 6; ++i)  s_red[wid][21 + i] = G[i];
    }
    __syncthreads();
    if (t < NACC) {
        float v = s_red[0][t] + s_red[1][t] + s_red[2][t] + s_red[3][t];
        // transposed layout: [b][counter][block] -> contiguous rows for the solve
        partials[((long)b * NACC + t) * BLOCKS_PER_B + blk] = v;
    }
}

// ---------------- Pass 2: assemble + 6x6 solve per batch ----------------
__global__ void dba_solve(
    const float* __restrict__ partials, const float* __restrict__ lmbda,
    const int* __restrict__ iter_idx,
    float* __restrict__ out_pose,      // d_out[0:96], clipped
    float* __restrict__ dp_raw)        // ws, unclipped (for pass 3)
{
    const int b = blockIdx.x;
    const int t = threadIdx.x;   // 64 threads
    __shared__ float s[NACC];
    if (t < NACC) {
        const float4* p4 = (const float4*)(partials + ((long)b * NACC + t) * BLOCKS_PER_B);
        float4 a = make_float4(0.f, 0.f, 0.f, 0.f);
#pragma unroll
        for (int k = 0; k < BLOCKS_PER_B / 4; ++k) {
            float4 v = p4[k];
            a.x += v.x; a.y += v.y; a.z += v.z; a.w += v.w;
        }
        s[t] = (a.x + a.y) + (a.z + a.w);
    }
    __syncthreads();
    if (t != 0) return;

    const float lam = safe_lambda(lmbda[b]);
    float H[6][6], g[6];
    int idx = 0;
    for (int p = 0; p < 6; ++p)
        for (int q = p; q < 6; ++q) {
            float v = s[idx];                 // already Hpp - term_to_sub
            H[p][q] = v; H[q][p] = v;
            idx++;
        }
    for (int p = 0; p < 6; ++p) g[p] = s[21 + p];
    for (int p = 0; p < 6; ++p) H[p][p] += lam;

    if (*iter_idx >= 2) {
        for (int p = 3; p < 6; ++p) g[p] = 0.0f;
        for (int p = 3; p < 6; ++p)
            for (int q = 3; q < 6; ++q) H[p][q] += 1e8f;
    }
    for (int p = 0; p < 6; ++p) H[p][p] += 1.0f;
    for (int p = 0; p < 6; ++p) H[p][p] += 0.01f * H[p][p];

    // Gaussian elimination with partial pivoting, augmented column = g
    float A[6][7];
    for (int p = 0; p < 6; ++p) {
        for (int q = 0; q < 6; ++q) A[p][q] = H[p][q];
        A[p][6] = g[p];
    }
    for (int col = 0; col < 6; ++col) {
        int piv = col; float best = fabsf(A[col][col]);
        for (int rr = col + 1; rr < 6; ++rr) {
            float v = fabsf(A[rr][col]);
            if (v > best) { best = v; piv = rr; }
        }
        if (piv != col)
            for (int cc = col; cc < 7; ++cc) {
                float tmp = A[col][cc]; A[col][cc] = A[piv][cc]; A[piv][cc] = tmp;
            }
        const float invp = 1.0f / A[col][col];
        for (int rr = col + 1; rr < 6; ++rr) {
            const float f = A[rr][col] * invp;
            for (int cc = col; cc < 7; ++cc) A[rr][cc] -= f * A[col][cc];
        }
    }
    float x[6];
    for (int rr = 5; rr >= 0; --rr) {
        float v = A[rr][6];
        for (int cc = rr + 1; cc < 6; ++cc) v -= A[rr][cc] * x[cc];
        x[rr] = v / A[rr][rr];
    }
    for (int p = 0; p < 6; ++p) {
        dp_raw[b * 6 + p] = x[p];                       // unclipped, feeds pass 3
        out_pose[b * 6 + p] = fminf(fmaxf(x[p], -2.0f), 2.0f);
    }
}

// ---------------- Pass 3: delta_depth per point ----------------
__device__ __forceinline__ float depth_pt(const Pt& P, float lam, const float (&dp)[6])
{
    float jp[12] = {P.a0.x, P.a0.y, P.a0.z, P.a0.w,
                    P.a1.x, P.a1.y, P.a1.z, P.a1.w,
                    P.a2.x, P.a2.y, P.a2.z, P.a2.w};
    const float conf = P.wv.x, nl = P.wv.y;
    const float jdx = P.jd.x, jdy = P.jd.y;
    const float rx  = P.rv.x, ry  = P.rv.y;

    float v = 0.0f;
#pragma unroll
    for (int p = 0; p < 6; ++p) {
        const float h = conf * (jp[p] * jdx + jp[6 + p] * jdy);
        v += h * dp[p];
    }
    const float Hdd = conf * (jdx * jdx + jdy * jdy);
    const float gd  = conf * (jdx * rx + jdy * ry);
    const float inv = 1.0f / fmaxf(Hdd + lam + nl + 1e-4f, 1e-4f);
    float dd = inv * (gd - v);
    return fminf(fmaxf(dd, -5.0f), 5.0f);
}

__global__ __launch_bounds__(THREADS) void dba_pass3(
    const float* __restrict__ r, const float* __restrict__ w,
    const float* __restrict__ Jp, const float* __restrict__ Jd,
    const float* __restrict__ lmbda, const float* __restrict__ dp_raw,
    float* __restrict__ out_dd)
{
    const int b   = blockIdx.y;
    const int blk = blockIdx.x;
    const int t   = threadIdx.x;
    const float lam = safe_lambda(lmbda[b]);

    float dp[6];
#pragma unroll
    for (int p = 0; p < 6; ++p) dp[p] = dp_raw[b * 6 + p];

    const long base = (long)b * NPB + (long)blk * (THREADS * PPT) + t;

    Pt A, B;
    load_pt(Jp, Jd, r, w, base + 0 * THREADS, A);
#pragma unroll
    for (int it = 0; it < PPT; it += 2) {
        load_pt(Jp, Jd, r, w, base + (it + 1) * THREADS, B);
        out_dd[base + it * THREADS] = depth_pt(A, lam, dp);
        if (it + 2 < PPT)
            load_pt(Jp, Jd, r, w, base + (it + 2) * THREADS, A);
        out_dd[base + (it + 1) * THREADS] = depth_pt(B, lam, dp);
    }
}

extern "C" void kernel_launch(void* const* d_in, const int* in_sizes, int n_in,
                              void* d_out, int out_size, void* d_ws, size_t ws_size,
                              hipStream_t stream) {
    const float* r     = (const float*)d_in[0];
    const float* w     = (const float*)d_in[1];
    const float* Jp    = (const float*)d_in[2];
    const float* Jd    = (const float*)d_in[3];
    const float* lmbda = (const float*)d_in[4];
    const int*   iter  = (const int*)  d_in[5];

    float* out      = (float*)d_out;           // [0:96) delta_pose, [96:) delta_depth
    float* partials = (float*)d_ws;            // BATCH * NACC * BLOCKS_PER_B floats
    float* dp_raw   = partials + (long)BATCH * NACC * BLOCKS_PER_B;  // BATCH*6 floats

    dim3 grid(BLOCKS_PER_B, BATCH);
    dba_pass1<<<grid, THREADS, 0, stream>>>(r, w, Jp, Jd, lmbda, partials);
    dba_solve<<<BATCH, 64, 0, stream>>>(partials, lmbda, iter, out, dp_raw);
    dba_pass3<<<grid, THREADS, 0, stream>>>(r, w, Jp, Jd, lmbda, dp_raw, out + BATCH * 6);
}